// Round 1
// baseline (1808.394 us; speedup 1.0000x reference)
//
#include <hip/hip_runtime.h>

#define B_ 16
#define S_ 80
#define D_ 512
#define H_ 64
#define DI_ 2048
#define L_ 6
#define G4H 256            // 4*H
#define NROW (B_ * S_)     // 1280 rows = (b, s)
#define EPS_ 1e-6f

// ---------------- math helpers ----------------
__device__ __forceinline__ float sigmoidf_(float x) {
    return 1.0f / (1.0f + __expf(-x));
}
__device__ __forceinline__ float tanh_(float x) {
    // clamp avoids inf/inf NaN; e^30 is well inside fp32 range
    float xc = fminf(fmaxf(x, -15.0f), 15.0f);
    float t = __expf(2.0f * xc);
    return (t - 1.0f) / (t + 1.0f);
}

// ---------------- LayerNorm: one block per row, D=512, 256 threads ----------------
__global__ __launch_bounds__(256)
void ln_kernel(const float* __restrict__ x, const float* __restrict__ g,
               const float* __restrict__ b, float* __restrict__ out) {
    int row = blockIdx.x;
    int t = threadIdx.x;
    const float* xr = x + (size_t)row * D_;
    float v0 = xr[t], v1 = xr[t + 256];
    __shared__ float red[256];
    red[t] = v0 + v1;
    __syncthreads();
    for (int o = 128; o > 0; o >>= 1) { if (t < o) red[t] += red[t + o]; __syncthreads(); }
    float m = red[0] * (1.0f / (float)D_);
    __syncthreads();
    float d0 = v0 - m, d1 = v1 - m;
    red[t] = d0 * d0 + d1 * d1;
    __syncthreads();
    for (int o = 128; o > 0; o >>= 1) { if (t < o) red[t] += red[t + o]; __syncthreads(); }
    float rs = rsqrtf(red[0] * (1.0f / (float)D_) + EPS_);
    float* orow = out + (size_t)row * D_;
    orow[t]       = d0 * rs * g[t]       + b[t];
    orow[t + 256] = d1 * rs * g[t + 256] + b[t + 256];
}

// ---------------- generic fp32 GEMM: C[M,N] = A[M,K] @ W[N,K]^T (+bias)(+relu)(+res) ----------------
// Requires M%64==0, N%64==0, K%16==0 (true for all call sites).
template<int WITH_BIAS, int WITH_RELU, int WITH_RES>
__global__ __launch_bounds__(256)
void gemm_kernel(const float* __restrict__ A, const float* __restrict__ W,
                 const float* __restrict__ bias, const float* __restrict__ res,
                 float* __restrict__ C, int M, int N, int K) {
    const int BM = 64, BN = 64, BK = 16;
    __shared__ float As[BK][BM + 4];   // +4 keeps float4 alignment, 2-way bank alias (free)
    __shared__ float Ws[BK][BN + 4];
    int tid = threadIdx.x;
    int tx = tid & 15, ty = tid >> 4;
    int m0 = blockIdx.y * BM, n0 = blockIdx.x * BN;
    float acc[4][4] = {};
    for (int k0 = 0; k0 < K; k0 += BK) {
        #pragma unroll
        for (int i = 0; i < 4; i++) {
            int li = tid + i * 256;
            int r = li >> 4, c = li & 15;
            As[c][r] = A[(size_t)(m0 + r) * K + (k0 + c)];
            Ws[c][r] = W[(size_t)(n0 + r) * K + (k0 + c)];
        }
        __syncthreads();
        #pragma unroll
        for (int k = 0; k < BK; k++) {
            float4 av = *(const float4*)&As[k][ty * 4];
            float4 wv = *(const float4*)&Ws[k][tx * 4];
            float a[4] = {av.x, av.y, av.z, av.w};
            float w[4] = {wv.x, wv.y, wv.z, wv.w};
            #pragma unroll
            for (int i = 0; i < 4; i++)
                #pragma unroll
                for (int j = 0; j < 4; j++)
                    acc[i][j] = fmaf(a[i], w[j], acc[i][j]);
        }
        __syncthreads();
    }
    #pragma unroll
    for (int i = 0; i < 4; i++) {
        int m = m0 + ty * 4 + i;
        int n = n0 + tx * 4;
        float4 v = make_float4(acc[i][0], acc[i][1], acc[i][2], acc[i][3]);
        if (WITH_BIAS) {
            float4 bv = *(const float4*)&bias[n];
            v.x += bv.x; v.y += bv.y; v.z += bv.z; v.w += bv.w;
        }
        if (WITH_RELU) {
            v.x = fmaxf(v.x, 0.f); v.y = fmaxf(v.y, 0.f);
            v.z = fmaxf(v.z, 0.f); v.w = fmaxf(v.w, 0.f);
        }
        if (WITH_RES) {
            float4 rv = *(const float4*)&res[(size_t)m * N + n];
            v.x += rv.x; v.y += rv.y; v.z += rv.z; v.w += rv.w;
        }
        *(float4*)&C[(size_t)m * N + n] = v;
    }
}

// ---------------- LSTM scan over the janossy permutations ----------------
// One block per sequence (i = output position, b = batch). 256 threads; thread g
// owns gate row whh[g, 0:64] in registers. h broadcast via LDS, c in lane regs.
// Permutation applied as an index formula on the precomputed projections xg[B,S,4H].
__global__ __launch_bounds__(256)
void lstm_kernel(const float* __restrict__ xg,   // [B, S, 4H]
                 const float* __restrict__ whh,  // [4H, H]
                 float* __restrict__ hlast) {    // [B, S, H]
    int seq = blockIdx.x;          // 0..1279
    int i = seq / B_;              // output position
    int b = seq - i * B_;          // batch
    int g = threadIdx.x;           // gate index 0..255

    float w[H_];
    #pragma unroll
    for (int k = 0; k < H_; k++) w[k] = whh[g * H_ + k];

    __shared__ float hs[H_];
    __shared__ float gs[G4H];
    if (g < H_) hs[g] = 0.0f;
    float c = 0.0f;

    const float* xgb = xg + (size_t)b * S_ * G4H;
    for (int t = 0; t < S_; t++) {
        int src = (t == i) ? (S_ - 1) : ((t == S_ - 1) ? i : t);
        float acc = xgb[src * G4H + g];
        __syncthreads();            // h from previous step visible; prev gates consumed
        #pragma unroll
        for (int k = 0; k < H_; k++) acc = fmaf(w[k], hs[k], acc);
        gs[g] = acc;
        __syncthreads();            // all gate dots done before h/c update
        if (g < H_) {
            float ig = sigmoidf_(gs[g]);
            float fg = sigmoidf_(gs[H_ + g]);
            float gg = tanh_(gs[2 * H_ + g]);
            float og = sigmoidf_(gs[3 * H_ + g]);
            c = fg * c + ig * gg;
            hs[g] = og * tanh_(c);
        }
    }
    __syncthreads();
    if (g < H_) hlast[((size_t)b * S_ + i) * H_ + g] = hs[g];
}

// ---------------- final LN + projection to one logit per row ----------------
__global__ __launch_bounds__(256)
void final_kernel(const float* __restrict__ x, const float* __restrict__ g,
                  const float* __restrict__ b, const float* __restrict__ wprj,
                  float* __restrict__ out) {
    int row = blockIdx.x;
    int t = threadIdx.x;
    const float* xr = x + (size_t)row * D_;
    float v0 = xr[t], v1 = xr[t + 256];
    __shared__ float red[256];
    red[t] = v0 + v1;
    __syncthreads();
    for (int o = 128; o > 0; o >>= 1) { if (t < o) red[t] += red[t + o]; __syncthreads(); }
    float m = red[0] * (1.0f / (float)D_);
    __syncthreads();
    float d0 = v0 - m, d1 = v1 - m;
    red[t] = d0 * d0 + d1 * d1;
    __syncthreads();
    for (int o = 128; o > 0; o >>= 1) { if (t < o) red[t] += red[t + o]; __syncthreads(); }
    float rs = rsqrtf(red[0] * (1.0f / (float)D_) + EPS_);
    __syncthreads();
    float y0 = (d0 * rs * g[t] + b[t]) * wprj[t];
    float y1 = (d1 * rs * g[t + 256] + b[t + 256]) * wprj[t + 256];
    red[t] = y0 + y1;
    __syncthreads();
    for (int o = 128; o > 0; o >>= 1) { if (t < o) red[t] += red[t + o]; __syncthreads(); }
    if (t == 0) out[row] = red[0];
}

// ---------------- host ----------------
extern "C" void kernel_launch(void* const* d_in, const int* in_sizes, int n_in,
                              void* d_out, int out_size, void* d_ws, size_t ws_size,
                              hipStream_t stream) {
    const float* src   = (const float*)d_in[0];
    // d_in[1] = trg_seq: unused by the reference
    const float* ln1_g = (const float*)d_in[2];
    const float* ln1_b = (const float*)d_in[3];
    const float* wih   = (const float*)d_in[4];   // [L, 4H, D]
    const float* whh   = (const float*)d_in[5];   // [L, 4H, H]
    const float* wfc   = (const float*)d_in[6];   // [L, D, H]
    const float* ln2_g = (const float*)d_in[7];
    const float* ln2_b = (const float*)d_in[8];
    const float* w1    = (const float*)d_in[9];   // [L, DI, D]
    const float* b1    = (const float*)d_in[10];  // [L, DI]
    const float* w2    = (const float*)d_in[11];  // [L, D, DI]
    const float* b2    = (const float*)d_in[12];  // [L, D]
    const float* lnf_g = (const float*)d_in[13];
    const float* lnf_b = (const float*)d_in[14];
    const float* wprj  = (const float*)d_in[15];  // [1, D]
    float* out = (float*)d_out;

    float* ws    = (float*)d_ws;
    float* xcur  = ws;                                  // NROW*D   = 655360
    float* lnbuf = xcur  + (size_t)NROW * D_;           // NROW*D   = 655360
    float* xgbuf = lnbuf + (size_t)NROW * D_;           // NROW*4H  = 327680
    float* hbuf  = xgbuf + (size_t)NROW * G4H;          // NROW*H   =  81920
    float* f1buf = hbuf  + (size_t)NROW * H_;           // NROW*DI  = 2621440

    hipMemcpyAsync(xcur, src, (size_t)NROW * D_ * sizeof(float),
                   hipMemcpyDeviceToDevice, stream);

    for (int l = 0; l < L_; l++) {
        // --- janossy layer ---
        ln_kernel<<<NROW, 256, 0, stream>>>(xcur, ln1_g + (size_t)l * D_,
                                            ln1_b + (size_t)l * D_, lnbuf);
        // xg[b,s,:] = LN(x)[b,s,:] @ wih_l^T   -> [B,S,4H]
        gemm_kernel<0, 0, 0><<<dim3(G4H / 64, NROW / 64), 256, 0, stream>>>(
            lnbuf, wih + (size_t)l * G4H * D_, nullptr, nullptr, xgbuf,
            NROW, G4H, D_);
        lstm_kernel<<<NROW, 256, 0, stream>>>(xgbuf, whh + (size_t)l * G4H * H_, hbuf);
        // x = h @ wfc^T + x   (in-place residual on xcur is safe: 1 read + 1 write per elem)
        gemm_kernel<0, 0, 1><<<dim3(D_ / 64, NROW / 64), 256, 0, stream>>>(
            hbuf, wfc + (size_t)l * D_ * H_, nullptr, xcur, xcur,
            NROW, D_, H_);
        // --- FFN ---
        ln_kernel<<<NROW, 256, 0, stream>>>(xcur, ln2_g + (size_t)l * D_,
                                            ln2_b + (size_t)l * D_, lnbuf);
        gemm_kernel<1, 1, 0><<<dim3(DI_ / 64, NROW / 64), 256, 0, stream>>>(
            lnbuf, w1 + (size_t)l * DI_ * D_, b1 + (size_t)l * DI_, nullptr, f1buf,
            NROW, DI_, D_);
        gemm_kernel<1, 0, 1><<<dim3(D_ / 64, NROW / 64), 256, 0, stream>>>(
            f1buf, w2 + (size_t)l * D_ * DI_, b2 + (size_t)l * D_, xcur, xcur,
            NROW, D_, DI_);
    }
    final_kernel<<<NROW, 256, 0, stream>>>(xcur, lnf_g, lnf_b, wprj, out);
}

// Round 2
// 1072.595 us; speedup vs baseline: 1.6860x; 1.6860x over previous
//
#include <hip/hip_runtime.h>
#include <hip/hip_bf16.h>

#define B_ 16
#define S_ 80
#define D_ 512
#define H_ 64
#define DI_ 2048
#define L_ 6
#define G4H 256            // 4*H
#define NROW (B_ * S_)     // 1280 rows = (b, s)
#define EPS_ 1e-6f

typedef __attribute__((ext_vector_type(8))) short short8;
typedef __attribute__((ext_vector_type(4))) float f32x4;

// ---------------- math helpers ----------------
__device__ __forceinline__ float sigmoidf_(float x) {
    return 1.0f / (1.0f + __expf(-x));
}
__device__ __forceinline__ float tanh_(float x) {
    float xc = fminf(fmaxf(x, -15.0f), 15.0f);
    float t = __expf(2.0f * xc);
    return (t - 1.0f) / (t + 1.0f);
}
__device__ __forceinline__ short f2bf(float f) {
    __hip_bfloat16 h = __float2bfloat16(f);   // RNE
    return *reinterpret_cast<short*>(&h);
}

// ---------------- LayerNorm: one block per row, D=512, 256 threads; bf16 out ----------------
__global__ __launch_bounds__(256)
void ln_kernel(const float* __restrict__ x, const float* __restrict__ g,
               const float* __restrict__ b, __hip_bfloat16* __restrict__ out) {
    int row = blockIdx.x;
    int t = threadIdx.x;
    const float* xr = x + (size_t)row * D_;
    float v0 = xr[t], v1 = xr[t + 256];
    __shared__ float red[256];
    red[t] = v0 + v1;
    __syncthreads();
    for (int o = 128; o > 0; o >>= 1) { if (t < o) red[t] += red[t + o]; __syncthreads(); }
    float m = red[0] * (1.0f / (float)D_);
    __syncthreads();
    float d0 = v0 - m, d1 = v1 - m;
    red[t] = d0 * d0 + d1 * d1;
    __syncthreads();
    for (int o = 128; o > 0; o >>= 1) { if (t < o) red[t] += red[t + o]; __syncthreads(); }
    float rs = rsqrtf(red[0] * (1.0f / (float)D_) + EPS_);
    __hip_bfloat16* orow = out + (size_t)row * D_;
    orow[t]       = __float2bfloat16(d0 * rs * g[t]       + b[t]);
    orow[t + 256] = __float2bfloat16(d1 * rs * g[t + 256] + b[t + 256]);
}

// ---------------- bf16 MFMA GEMM: C[M,N] = A[M,K] @ W[N,K]^T (+bias)(+relu)(+res) -----------
// A is bf16 row-major; W is fp32 row-major [N,K], converted to bf16 during LDS staging.
// Accumulate fp32. Requires M%64==0, N%64==0, K%32==0 (true at all call sites).
// Tile: BM=64, BN=64, BK=32; 256 threads = 4 waves in 2x2, each wave 32x32 via
// 4x mfma_f32_16x16x32_bf16. LDS row stride 40 elems (80B): 16B-aligned, 2-way bank alias.
template<int WITH_BIAS, int WITH_RELU, int WITH_RES, int OUT_BF16>
__global__ __launch_bounds__(256)
void mfma_gemm(const __hip_bfloat16* __restrict__ A, const float* __restrict__ W,
               const float* __restrict__ bias, const float* __restrict__ res,
               void* __restrict__ C, int M, int N, int K) {
    const int LDT = 40;  // LDS row stride in bf16 elems
    __shared__ short As[64 * LDT];
    __shared__ short Ws[64 * LDT];

    int tid  = threadIdx.x;
    int wave = tid >> 6, lane = tid & 63;
    int quad = lane >> 4, l16 = lane & 15;
    int m_off = (wave >> 1) * 32, n_off = (wave & 1) * 32;
    int m0 = blockIdx.y * 64, n0 = blockIdx.x * 64;

    int r = tid >> 2, c = tid & 3;           // staging: row 0..63, 8-elem chunk 0..3
    const short* Ag = reinterpret_cast<const short*>(A);

    f32x4 acc00 = {0.f,0.f,0.f,0.f}, acc01 = acc00, acc10 = acc00, acc11 = acc00;

    for (int k0 = 0; k0 < K; k0 += 32) {
        // global -> regs
        short8 av = *reinterpret_cast<const short8*>(&Ag[(size_t)(m0 + r) * K + k0 + c * 8]);
        const float* wrow = &W[(size_t)(n0 + r) * K + k0 + c * 8];
        float4 w0 = *reinterpret_cast<const float4*>(wrow);
        float4 w1 = *reinterpret_cast<const float4*>(wrow + 4);
        short8 wv;
        wv[0] = f2bf(w0.x); wv[1] = f2bf(w0.y); wv[2] = f2bf(w0.z); wv[3] = f2bf(w0.w);
        wv[4] = f2bf(w1.x); wv[5] = f2bf(w1.y); wv[6] = f2bf(w1.z); wv[7] = f2bf(w1.w);

        __syncthreads();   // previous iter's frag reads complete before overwrite
        *reinterpret_cast<short8*>(&As[r * LDT + c * 8]) = av;
        *reinterpret_cast<short8*>(&Ws[r * LDT + c * 8]) = wv;
        __syncthreads();

        short8 a0 = *reinterpret_cast<const short8*>(&As[(m_off + l16) * LDT + quad * 8]);
        short8 a1 = *reinterpret_cast<const short8*>(&As[(m_off + 16 + l16) * LDT + quad * 8]);
        short8 b0 = *reinterpret_cast<const short8*>(&Ws[(n_off + l16) * LDT + quad * 8]);
        short8 b1 = *reinterpret_cast<const short8*>(&Ws[(n_off + 16 + l16) * LDT + quad * 8]);

        acc00 = __builtin_amdgcn_mfma_f32_16x16x32_bf16(a0, b0, acc00, 0, 0, 0);
        acc01 = __builtin_amdgcn_mfma_f32_16x16x32_bf16(a0, b1, acc01, 0, 0, 0);
        acc10 = __builtin_amdgcn_mfma_f32_16x16x32_bf16(a1, b0, acc10, 0, 0, 0);
        acc11 = __builtin_amdgcn_mfma_f32_16x16x32_bf16(a1, b1, acc11, 0, 0, 0);
    }

    // Epilogue. C/D layout: col = lane&15, row = quad*4 + reg  [m89-verified]
    f32x4 accs[2][2] = {{acc00, acc01}, {acc10, acc11}};
    #pragma unroll
    for (int fi = 0; fi < 2; fi++) {
        #pragma unroll
        for (int fj = 0; fj < 2; fj++) {
            int coln = n0 + n_off + fj * 16 + l16;
            float bv = WITH_BIAS ? bias[coln] : 0.0f;
            #pragma unroll
            for (int rr = 0; rr < 4; rr++) {
                int rowm = m0 + m_off + fi * 16 + quad * 4 + rr;
                float v = accs[fi][fj][rr];
                if (WITH_BIAS) v += bv;
                if (WITH_RELU) v = fmaxf(v, 0.0f);
                if (WITH_RES)  v += res[(size_t)rowm * N + coln];
                if (OUT_BF16)
                    reinterpret_cast<__hip_bfloat16*>(C)[(size_t)rowm * N + coln] = __float2bfloat16(v);
                else
                    reinterpret_cast<float*>(C)[(size_t)rowm * N + coln] = v;
            }
        }
    }
}

// ---------------- LSTM scan over the janossy permutations (fp32 recurrence) ----------------
__global__ __launch_bounds__(256)
void lstm_kernel(const float* __restrict__ xg,   // [B, S, 4H] fp32
                 const float* __restrict__ whh,  // [4H, H] fp32
                 __hip_bfloat16* __restrict__ hlast) {  // [B, S, H] bf16
    int seq = blockIdx.x;          // 0..1279
    int i = seq / B_;              // output position
    int b = seq - i * B_;          // batch
    int g = threadIdx.x;           // gate index 0..255

    float w[H_];
    #pragma unroll
    for (int k = 0; k < H_; k++) w[k] = whh[g * H_ + k];

    __shared__ float hs[H_];
    __shared__ float gs[G4H];
    if (g < H_) hs[g] = 0.0f;
    float c = 0.0f;

    const float* xgb = xg + (size_t)b * S_ * G4H;
    for (int t = 0; t < S_; t++) {
        int src = (t == i) ? (S_ - 1) : ((t == S_ - 1) ? i : t);
        float acc = xgb[src * G4H + g];
        __syncthreads();
        #pragma unroll
        for (int k = 0; k < H_; k++) acc = fmaf(w[k], hs[k], acc);
        gs[g] = acc;
        __syncthreads();
        if (g < H_) {
            float ig = sigmoidf_(gs[g]);
            float fg = sigmoidf_(gs[H_ + g]);
            float gg = tanh_(gs[2 * H_ + g]);
            float og = sigmoidf_(gs[3 * H_ + g]);
            c = fg * c + ig * gg;
            hs[g] = og * tanh_(c);
        }
    }
    __syncthreads();
    if (g < H_) hlast[((size_t)b * S_ + i) * H_ + g] = __float2bfloat16(hs[g]);
}

// ---------------- final LN + projection to one logit per row ----------------
__global__ __launch_bounds__(256)
void final_kernel(const float* __restrict__ x, const float* __restrict__ g,
                  const float* __restrict__ b, const float* __restrict__ wprj,
                  float* __restrict__ out) {
    int row = blockIdx.x;
    int t = threadIdx.x;
    const float* xr = x + (size_t)row * D_;
    float v0 = xr[t], v1 = xr[t + 256];
    __shared__ float red[256];
    red[t] = v0 + v1;
    __syncthreads();
    for (int o = 128; o > 0; o >>= 1) { if (t < o) red[t] += red[t + o]; __syncthreads(); }
    float m = red[0] * (1.0f / (float)D_);
    __syncthreads();
    float d0 = v0 - m, d1 = v1 - m;
    red[t] = d0 * d0 + d1 * d1;
    __syncthreads();
    for (int o = 128; o > 0; o >>= 1) { if (t < o) red[t] += red[t + o]; __syncthreads(); }
    float rs = rsqrtf(red[0] * (1.0f / (float)D_) + EPS_);
    __syncthreads();
    float y0 = (d0 * rs * g[t] + b[t]) * wprj[t];
    float y1 = (d1 * rs * g[t + 256] + b[t + 256]) * wprj[t + 256];
    red[t] = y0 + y1;
    __syncthreads();
    for (int o = 128; o > 0; o >>= 1) { if (t < o) red[t] += red[t + o]; __syncthreads(); }
    if (t == 0) out[row] = red[0];
}

// ---------------- host ----------------
extern "C" void kernel_launch(void* const* d_in, const int* in_sizes, int n_in,
                              void* d_out, int out_size, void* d_ws, size_t ws_size,
                              hipStream_t stream) {
    const float* src   = (const float*)d_in[0];
    const float* ln1_g = (const float*)d_in[2];
    const float* ln1_b = (const float*)d_in[3];
    const float* wih   = (const float*)d_in[4];   // [L, 4H, D]
    const float* whh   = (const float*)d_in[5];   // [L, 4H, H]
    const float* wfc   = (const float*)d_in[6];   // [L, D, H]
    const float* ln2_g = (const float*)d_in[7];
    const float* ln2_b = (const float*)d_in[8];
    const float* w1    = (const float*)d_in[9];   // [L, DI, D]
    const float* b1    = (const float*)d_in[10];  // [L, DI]
    const float* w2    = (const float*)d_in[11];  // [L, D, DI]
    const float* b2    = (const float*)d_in[12];  // [L, D]
    const float* lnf_g = (const float*)d_in[13];
    const float* lnf_b = (const float*)d_in[14];
    const float* wprj  = (const float*)d_in[15];  // [1, D]
    float* out = (float*)d_out;

    char* ws = (char*)d_ws;
    float* xcur = (float*)ws;                       ws += (size_t)NROW * D_  * 4;  // fp32 residual stream
    __hip_bfloat16* lnb = (__hip_bfloat16*)ws;      ws += (size_t)NROW * D_  * 2;  // LN output (bf16 A-operand)
    float* xg   = (float*)ws;                       ws += (size_t)NROW * G4H * 4;  // gate projections (fp32 for LSTM)
    __hip_bfloat16* hb  = (__hip_bfloat16*)ws;      ws += (size_t)NROW * H_  * 2;  // LSTM h (bf16 A-operand)
    __hip_bfloat16* f1  = (__hip_bfloat16*)ws;      ws += (size_t)NROW * DI_ * 2;  // FFN hidden (bf16 A-operand)

    hipMemcpyAsync(xcur, src, (size_t)NROW * D_ * sizeof(float),
                   hipMemcpyDeviceToDevice, stream);

    for (int l = 0; l < L_; l++) {
        // --- janossy layer ---
        ln_kernel<<<NROW, 256, 0, stream>>>(xcur, ln1_g + (size_t)l * D_,
                                            ln1_b + (size_t)l * D_, lnb);
        // xg = LN(x) @ wih^T  [1280, 256], fp32 out
        mfma_gemm<0, 0, 0, 0><<<dim3(G4H / 64, NROW / 64), 256, 0, stream>>>(
            lnb, wih + (size_t)l * G4H * D_, nullptr, nullptr, xg, NROW, G4H, D_);
        lstm_kernel<<<NROW, 256, 0, stream>>>(xg, whh + (size_t)l * G4H * H_, hb);
        // x = h @ wfc^T + x
        mfma_gemm<0, 0, 1, 0><<<dim3(D_ / 64, NROW / 64), 256, 0, stream>>>(
            hb, wfc + (size_t)l * D_ * H_, nullptr, xcur, xcur, NROW, D_, H_);
        // --- FFN ---
        ln_kernel<<<NROW, 256, 0, stream>>>(xcur, ln2_g + (size_t)l * D_,
                                            ln2_b + (size_t)l * D_, lnb);
        // f1 = relu(LN(x) @ w1^T + b1), bf16 out
        mfma_gemm<1, 1, 0, 1><<<dim3(DI_ / 64, NROW / 64), 256, 0, stream>>>(
            lnb, w1 + (size_t)l * DI_ * D_, b1 + (size_t)l * DI_, nullptr, f1, NROW, DI_, D_);
        // x = f1 @ w2^T + b2 + x
        mfma_gemm<1, 0, 1, 0><<<dim3(D_ / 64, NROW / 64), 256, 0, stream>>>(
            f1, w2 + (size_t)l * D_ * DI_, b2 + (size_t)l * D_, xcur, xcur, NROW, D_, DI_);
    }
    final_kernel<<<NROW, 256, 0, stream>>>(xcur, lnf_g, lnf_b, wprj, out);
}

// Round 3
// 1054.277 us; speedup vs baseline: 1.7153x; 1.0174x over previous
//
#include <hip/hip_runtime.h>
#include <hip/hip_bf16.h>

#define B_ 16
#define S_ 80
#define D_ 512
#define H_ 64
#define DI_ 2048
#define L_ 6
#define G4H 256            // 4*H
#define NROW (B_ * S_)     // 1280 rows = (b, s)
#define EPS_ 1e-6f

typedef __attribute__((ext_vector_type(8))) short short8;
typedef __attribute__((ext_vector_type(4))) float f32x4;

// ---------------- math helpers ----------------
__device__ __forceinline__ float sigmoidf_(float x) {
    return __fdividef(1.0f, 1.0f + __expf(-x));
}
__device__ __forceinline__ float tanh_(float x) {
    // 2*sigmoid(2x)-1; saturates cleanly at +-1 in fp32 (no NaN for finite x)
    return __fdividef(2.0f, 1.0f + __expf(-2.0f * x)) - 1.0f;
}
__device__ __forceinline__ short f2bf(float f) {
    __hip_bfloat16 h = __float2bfloat16(f);   // RNE
    return *reinterpret_cast<short*>(&h);
}

// ---------------- LayerNorm: one block per row, D=512, 256 threads; bf16 out ----------------
__global__ __launch_bounds__(256)
void ln_kernel(const float* __restrict__ x, const float* __restrict__ g,
               const float* __restrict__ b, __hip_bfloat16* __restrict__ out) {
    int row = blockIdx.x;
    int t = threadIdx.x;
    const float* xr = x + (size_t)row * D_;
    float v0 = xr[t], v1 = xr[t + 256];
    __shared__ float red[256];
    red[t] = v0 + v1;
    __syncthreads();
    for (int o = 128; o > 0; o >>= 1) { if (t < o) red[t] += red[t + o]; __syncthreads(); }
    float m = red[0] * (1.0f / (float)D_);
    __syncthreads();
    float d0 = v0 - m, d1 = v1 - m;
    red[t] = d0 * d0 + d1 * d1;
    __syncthreads();
    for (int o = 128; o > 0; o >>= 1) { if (t < o) red[t] += red[t + o]; __syncthreads(); }
    float rs = rsqrtf(red[0] * (1.0f / (float)D_) + EPS_);
    __hip_bfloat16* orow = out + (size_t)row * D_;
    orow[t]       = __float2bfloat16(d0 * rs * g[t]       + b[t]);
    orow[t + 256] = __float2bfloat16(d1 * rs * g[t + 256] + b[t + 256]);
}

// ---------------- bf16 MFMA GEMM: C[M,N] = A[M,K] @ W[N,K]^T (+bias)(+relu)(+res) -----------
template<int WITH_BIAS, int WITH_RELU, int WITH_RES, int OUT_BF16>
__global__ __launch_bounds__(256)
void mfma_gemm(const __hip_bfloat16* __restrict__ A, const float* __restrict__ W,
               const float* __restrict__ bias, const float* __restrict__ res,
               void* __restrict__ C, int M, int N, int K) {
    const int LDT = 40;  // LDS row stride in bf16 elems
    __shared__ short As[64 * LDT];
    __shared__ short Ws[64 * LDT];

    int tid  = threadIdx.x;
    int wave = tid >> 6, lane = tid & 63;
    int quad = lane >> 4, l16 = lane & 15;
    int m_off = (wave >> 1) * 32, n_off = (wave & 1) * 32;
    int m0 = blockIdx.y * 64, n0 = blockIdx.x * 64;

    int r = tid >> 2, c = tid & 3;           // staging: row 0..63, 8-elem chunk 0..3
    const short* Ag = reinterpret_cast<const short*>(A);

    f32x4 acc00 = {0.f,0.f,0.f,0.f}, acc01 = acc00, acc10 = acc00, acc11 = acc00;

    for (int k0 = 0; k0 < K; k0 += 32) {
        short8 av = *reinterpret_cast<const short8*>(&Ag[(size_t)(m0 + r) * K + k0 + c * 8]);
        const float* wrow = &W[(size_t)(n0 + r) * K + k0 + c * 8];
        float4 w0 = *reinterpret_cast<const float4*>(wrow);
        float4 w1 = *reinterpret_cast<const float4*>(wrow + 4);
        short8 wv;
        wv[0] = f2bf(w0.x); wv[1] = f2bf(w0.y); wv[2] = f2bf(w0.z); wv[3] = f2bf(w0.w);
        wv[4] = f2bf(w1.x); wv[5] = f2bf(w1.y); wv[6] = f2bf(w1.z); wv[7] = f2bf(w1.w);

        __syncthreads();
        *reinterpret_cast<short8*>(&As[r * LDT + c * 8]) = av;
        *reinterpret_cast<short8*>(&Ws[r * LDT + c * 8]) = wv;
        __syncthreads();

        short8 a0 = *reinterpret_cast<const short8*>(&As[(m_off + l16) * LDT + quad * 8]);
        short8 a1 = *reinterpret_cast<const short8*>(&As[(m_off + 16 + l16) * LDT + quad * 8]);
        short8 b0 = *reinterpret_cast<const short8*>(&Ws[(n_off + l16) * LDT + quad * 8]);
        short8 b1 = *reinterpret_cast<const short8*>(&Ws[(n_off + 16 + l16) * LDT + quad * 8]);

        acc00 = __builtin_amdgcn_mfma_f32_16x16x32_bf16(a0, b0, acc00, 0, 0, 0);
        acc01 = __builtin_amdgcn_mfma_f32_16x16x32_bf16(a0, b1, acc01, 0, 0, 0);
        acc10 = __builtin_amdgcn_mfma_f32_16x16x32_bf16(a1, b0, acc10, 0, 0, 0);
        acc11 = __builtin_amdgcn_mfma_f32_16x16x32_bf16(a1, b1, acc11, 0, 0, 0);
    }

    f32x4 accs[2][2] = {{acc00, acc01}, {acc10, acc11}};
    #pragma unroll
    for (int fi = 0; fi < 2; fi++) {
        #pragma unroll
        for (int fj = 0; fj < 2; fj++) {
            int coln = n0 + n_off + fj * 16 + l16;
            float bv = WITH_BIAS ? bias[coln] : 0.0f;
            #pragma unroll
            for (int rr = 0; rr < 4; rr++) {
                int rowm = m0 + m_off + fi * 16 + quad * 4 + rr;
                float v = accs[fi][fj][rr];
                if (WITH_BIAS) v += bv;
                if (WITH_RELU) v = fmaxf(v, 0.0f);
                if (WITH_RES)  v += res[(size_t)rowm * N + coln];
                if (OUT_BF16)
                    reinterpret_cast<__hip_bfloat16*>(C)[(size_t)rowm * N + coln] = __float2bfloat16(v);
                else
                    reinterpret_cast<float*>(C)[(size_t)rowm * N + coln] = v;
            }
        }
    }
}

// ---------------- MFMA LSTM over the janossy permutations ----------------
// One block per output position i (80 blocks, 256 thr = 4 waves). Block batches the
// M=16 batch elements; per step the recurrence h@whh^T is a 16x256x64 GEMM done as
// 8 mfma_f32_16x16x32_bf16 per wave. Gate columns are permuted so wave w / tile g /
// lane-col l16 <-> original column g*64 + w*16 + l16: each lane then holds i,f,g,o
// for the same (batch, hidden) in the same acc reg -> lane-local c update in fp32.
// h round-trips through padded LDS (144B row stride) as next step's bf16 A-operand.
__global__ __launch_bounds__(256)
void lstm_mfma_kernel(const float* __restrict__ xg,   // [B, S, 4H] fp32
                      const float* __restrict__ whh,  // [4H, H] fp32
                      __hip_bfloat16* __restrict__ hlast) {  // [B, S, H]
    const int i    = blockIdx.x;      // output position 0..79
    const int tid  = threadIdx.x;
    const int wave = tid >> 6;
    const int lane = tid & 63;
    const int quad = lane >> 4;
    const int l16  = lane & 15;
    const int hw   = wave * 16 + l16; // hidden unit this lane owns on the C side

    // B-fragments (whh -> bf16), loaded once. B-frag layout: lane l16 = column,
    // k = kc*32 + quad*8 + j. Permuted column n' -> original n = gate*64 + hw.
    short8 bfrag[4][2];
    #pragma unroll
    for (int gate = 0; gate < 4; gate++) {
        const float* wr = &whh[(size_t)(gate * 64 + hw) * H_];
        #pragma unroll
        for (int kc = 0; kc < 2; kc++) {
            float4 x0 = *(const float4*)(wr + kc * 32 + quad * 8);
            float4 x1 = *(const float4*)(wr + kc * 32 + quad * 8 + 4);
            short8 v;
            v[0] = f2bf(x0.x); v[1] = f2bf(x0.y); v[2] = f2bf(x0.z); v[3] = f2bf(x0.w);
            v[4] = f2bf(x1.x); v[5] = f2bf(x1.y); v[6] = f2bf(x1.z); v[7] = f2bf(x1.w);
            bfrag[gate][kc] = v;
        }
    }

    __shared__ __attribute__((aligned(16))) short hsh[16][72]; // h bf16, 144B rows

    float cst[4] = {0.f, 0.f, 0.f, 0.f};
    float hv[4];
    float xgv[4][4];   // xg for the current step: [gate][reg], reg r -> batch quad*4+r

    // prologue: t = 0 (h = c = 0 -> gates = xg)
    {
        int src0 = (i == 0) ? (S_ - 1) : 0;
        #pragma unroll
        for (int gate = 0; gate < 4; gate++)
            #pragma unroll
            for (int r = 0; r < 4; r++)
                xgv[gate][r] = xg[((size_t)(quad * 4 + r) * S_ + src0) * G4H + gate * 64 + hw];
        #pragma unroll
        for (int r = 0; r < 4; r++) {
            float ig = sigmoidf_(xgv[0][r]);
            float fg = sigmoidf_(xgv[1][r]);
            float gg = tanh_(xgv[2][r]);
            float og = sigmoidf_(xgv[3][r]);
            cst[r] = fg * cst[r] + ig * gg;
            hv[r]  = og * tanh_(cst[r]);
        }
        // next step's xg (software pipeline)
        int src1 = (1 == i) ? (S_ - 1) : 1;
        #pragma unroll
        for (int gate = 0; gate < 4; gate++)
            #pragma unroll
            for (int r = 0; r < 4; r++)
                xgv[gate][r] = xg[((size_t)(quad * 4 + r) * S_ + src1) * G4H + gate * 64 + hw];
    }

    for (int t = 1; t < S_; t++) {
        // publish h_{t-1}
        #pragma unroll
        for (int r = 0; r < 4; r++)
            hsh[quad * 4 + r][hw] = f2bf(hv[r]);
        __syncthreads();
        // A-frags: lane l16 = batch row, k = kc*32 + quad*8 + j
        short8 af0 = *reinterpret_cast<const short8*>(&hsh[l16][quad * 8]);
        short8 af1 = *reinterpret_cast<const short8*>(&hsh[l16][32 + quad * 8]);
        __syncthreads();   // reads done before next iter's writes

        f32x4 acc[4];
        #pragma unroll
        for (int gate = 0; gate < 4; gate++) {
            f32x4 a;
            a[0] = xgv[gate][0]; a[1] = xgv[gate][1];
            a[2] = xgv[gate][2]; a[3] = xgv[gate][3];
            acc[gate] = a;
        }
        #pragma unroll
        for (int gate = 0; gate < 4; gate++) {
            acc[gate] = __builtin_amdgcn_mfma_f32_16x16x32_bf16(af0, bfrag[gate][0], acc[gate], 0, 0, 0);
            acc[gate] = __builtin_amdgcn_mfma_f32_16x16x32_bf16(af1, bfrag[gate][1], acc[gate], 0, 0, 0);
        }

        // prefetch xg for t+1 while MFMA/nonlinearity retire
        if (t + 1 < S_) {
            int srcn = (t + 1 == i) ? (S_ - 1) : ((t + 1 == S_ - 1) ? i : (t + 1));
            #pragma unroll
            for (int gate = 0; gate < 4; gate++)
                #pragma unroll
                for (int r = 0; r < 4; r++)
                    xgv[gate][r] = xg[((size_t)(quad * 4 + r) * S_ + srcn) * G4H + gate * 64 + hw];
        }

        #pragma unroll
        for (int r = 0; r < 4; r++) {
            float ig = sigmoidf_(acc[0][r]);
            float fg = sigmoidf_(acc[1][r]);
            float gg = tanh_(acc[2][r]);
            float og = sigmoidf_(acc[3][r]);
            cst[r] = fg * cst[r] + ig * gg;
            hv[r]  = og * tanh_(cst[r]);
        }
    }

    // epilogue: hv = h_final for (batch quad*4+r, hidden hw)
    #pragma unroll
    for (int r = 0; r < 4; r++)
        hlast[((size_t)(quad * 4 + r) * S_ + i) * H_ + hw] = __float2bfloat16(hv[r]);
}

// ---------------- final LN + projection to one logit per row ----------------
__global__ __launch_bounds__(256)
void final_kernel(const float* __restrict__ x, const float* __restrict__ g,
                  const float* __restrict__ b, const float* __restrict__ wprj,
                  float* __restrict__ out) {
    int row = blockIdx.x;
    int t = threadIdx.x;
    const float* xr = x + (size_t)row * D_;
    float v0 = xr[t], v1 = xr[t + 256];
    __shared__ float red[256];
    red[t] = v0 + v1;
    __syncthreads();
    for (int o = 128; o > 0; o >>= 1) { if (t < o) red[t] += red[t + o]; __syncthreads(); }
    float m = red[0] * (1.0f / (float)D_);
    __syncthreads();
    float d0 = v0 - m, d1 = v1 - m;
    red[t] = d0 * d0 + d1 * d1;
    __syncthreads();
    for (int o = 128; o > 0; o >>= 1) { if (t < o) red[t] += red[t + o]; __syncthreads(); }
    float rs = rsqrtf(red[0] * (1.0f / (float)D_) + EPS_);
    __syncthreads();
    float y0 = (d0 * rs * g[t] + b[t]) * wprj[t];
    float y1 = (d1 * rs * g[t + 256] + b[t + 256]) * wprj[t + 256];
    red[t] = y0 + y1;
    __syncthreads();
    for (int o = 128; o > 0; o >>= 1) { if (t < o) red[t] += red[t + o]; __syncthreads(); }
    if (t == 0) out[row] = red[0];
}

// ---------------- host ----------------
extern "C" void kernel_launch(void* const* d_in, const int* in_sizes, int n_in,
                              void* d_out, int out_size, void* d_ws, size_t ws_size,
                              hipStream_t stream) {
    const float* src   = (const float*)d_in[0];
    const float* ln1_g = (const float*)d_in[2];
    const float* ln1_b = (const float*)d_in[3];
    const float* wih   = (const float*)d_in[4];   // [L, 4H, D]
    const float* whh   = (const float*)d_in[5];   // [L, 4H, H]
    const float* wfc   = (const float*)d_in[6];   // [L, D, H]
    const float* ln2_g = (const float*)d_in[7];
    const float* ln2_b = (const float*)d_in[8];
    const float* w1    = (const float*)d_in[9];   // [L, DI, D]
    const float* b1    = (const float*)d_in[10];  // [L, DI]
    const float* w2    = (const float*)d_in[11];  // [L, D, DI]
    const float* b2    = (const float*)d_in[12];  // [L, D]
    const float* lnf_g = (const float*)d_in[13];
    const float* lnf_b = (const float*)d_in[14];
    const float* wprj  = (const float*)d_in[15];  // [1, D]
    float* out = (float*)d_out;

    char* ws = (char*)d_ws;
    float* xcur = (float*)ws;                       ws += (size_t)NROW * D_  * 4;  // fp32 residual stream
    __hip_bfloat16* lnb = (__hip_bfloat16*)ws;      ws += (size_t)NROW * D_  * 2;  // LN output (bf16 A-operand)
    float* xg   = (float*)ws;                       ws += (size_t)NROW * G4H * 4;  // gate projections (fp32)
    __hip_bfloat16* hb  = (__hip_bfloat16*)ws;      ws += (size_t)NROW * H_  * 2;  // LSTM h (bf16 A-operand)
    __hip_bfloat16* f1  = (__hip_bfloat16*)ws;      ws += (size_t)NROW * DI_ * 2;  // FFN hidden (bf16 A-operand)

    hipMemcpyAsync(xcur, src, (size_t)NROW * D_ * sizeof(float),
                   hipMemcpyDeviceToDevice, stream);

    for (int l = 0; l < L_; l++) {
        // --- janossy layer ---
        ln_kernel<<<NROW, 256, 0, stream>>>(xcur, ln1_g + (size_t)l * D_,
                                            ln1_b + (size_t)l * D_, lnb);
        mfma_gemm<0, 0, 0, 0><<<dim3(G4H / 64, NROW / 64), 256, 0, stream>>>(
            lnb, wih + (size_t)l * G4H * D_, nullptr, nullptr, xg, NROW, G4H, D_);
        lstm_mfma_kernel<<<S_, 256, 0, stream>>>(xg, whh + (size_t)l * G4H * H_, hb);
        mfma_gemm<0, 0, 1, 0><<<dim3(D_ / 64, NROW / 64), 256, 0, stream>>>(
            hb, wfc + (size_t)l * D_ * H_, nullptr, xcur, xcur, NROW, D_, H_);
        // --- FFN ---
        ln_kernel<<<NROW, 256, 0, stream>>>(xcur, ln2_g + (size_t)l * D_,
                                            ln2_b + (size_t)l * D_, lnb);
        mfma_gemm<1, 1, 0, 1><<<dim3(DI_ / 64, NROW / 64), 256, 0, stream>>>(
            lnb, w1 + (size_t)l * DI_ * D_, b1 + (size_t)l * DI_, nullptr, f1, NROW, DI_, D_);
        mfma_gemm<1, 0, 1, 0><<<dim3(D_ / 64, NROW / 64), 256, 0, stream>>>(
            f1, w2 + (size_t)l * D_ * DI_, b2 + (size_t)l * D_, xcur, xcur, NROW, D_, DI_);
    }
    final_kernel<<<NROW, 256, 0, stream>>>(xcur, lnf_g, lnf_b, wprj, out);
}